// Round 5
// baseline (1032.102 us; speedup 1.0000x reference)
//
#include <hip/hip_runtime.h>

#define NSEQ 20000
#define TT 20
#define FD 128
#define EDG 640000
#define ETOT (EDG + NSEQ)

typedef short bf16x8 __attribute__((ext_vector_type(8)));
typedef float f32x4 __attribute__((ext_vector_type(4)));
typedef unsigned short u16;
typedef unsigned int u32;

__device__ __forceinline__ float bf2f(u16 h) {
  union { u32 u; float f; } v; v.u = ((u32)h) << 16; return v.f;
}
__device__ __forceinline__ u16 f2bf(float f) {
  union { float f; u32 u; } v; v.f = f;
  u32 u = v.u;
  return (u16)((u + 0x7fffu + ((u >> 16) & 1u)) >> 16);
}
__device__ __forceinline__ float sigm(float x) { return 1.0f / (1.0f + __expf(-x)); }
__device__ __forceinline__ float tanh_f(float x) { return 1.0f - 2.0f / (__expf(2.0f * x) + 1.0f); }
__device__ __forceinline__ int clampi(int v, int lo, int hi) {
  return v < lo ? lo : (v > hi ? hi : v);
}

// generic loaders over raw input (BF=1: bf16, BF=0: fp32)
template<int BF>
__device__ __forceinline__ bf16x8 ld8(const void* p, size_t i) {
  if (BF) return *(const bf16x8*)((const u16*)p + i);
  f32x4 a = *(const f32x4*)((const float*)p + i);
  f32x4 b = *(const f32x4*)((const float*)p + i + 4);
  bf16x8 r;
  r[0] = (short)f2bf(a[0]); r[1] = (short)f2bf(a[1]);
  r[2] = (short)f2bf(a[2]); r[3] = (short)f2bf(a[3]);
  r[4] = (short)f2bf(b[0]); r[5] = (short)f2bf(b[1]);
  r[6] = (short)f2bf(b[2]); r[7] = (short)f2bf(b[3]);
  return r;
}

// canonical-weights element offsets (u16 units) inside the canon block
#define OFF_WIHF 0
#define OFF_WHHF 65536
#define OFF_BF   131072
#define OFF_WIHB 131584
#define OFF_WHHB 197120
#define OFF_BB   262656
#define OFF_W1   263168
#define OFF_W2   394240
#define OFF_A1S  459776
#define OFF_A1D  460288
#define OFF_B1   460800
#define OFF_A2S  461312
#define OFF_A2D  461440
#define OFF_B2   461568
#define OFF_WFC  461696
#define OFF_BFC  462976

__global__ void k_detect(const u32* __restrict__ xw, int* __restrict__ flag) {
  if (threadIdx.x == 0 && blockIdx.x == 0) {
    int sane = 0;
    for (int i = 0; i < 32; ++i) {
      u16 lo = (u16)(xw[i] & 0xffffu);
      int e = (lo >> 7) & 0xff;
      sane += (e >= 100 && e <= 140) ? 1 : 0;
    }
    flag[0] = (sane >= 16) ? 1 : 0;   // 1 = bf16 inputs, 0 = fp32 inputs
  }
}

struct CvtArgs {
  const void* src[16];
  int off[16];
  int cnt[16];
};

template<int BF>
__global__ void k_cvt(CvtArgs a, u16* __restrict__ canon, const int* __restrict__ flag) {
  if (flag[0] != BF) return;
  int idx = blockIdx.x * 256 + threadIdx.x;
  int stride = gridDim.x * 256;
#pragma unroll 1
  for (int s = 0; s < 16; ++s) {
    const void* sp = a.src[s];
    int n = a.cnt[s], off = a.off[s];
    for (int i = idx; i < n; i += stride) {
      canon[off + i] = BF ? ((const u16*)sp)[i] : f2bf(((const float*)sp)[i]);
    }
  }
}

__global__ void k_fill0(u16* __restrict__ out, int n) {
  int i = blockIdx.x * 256 + threadIdx.x;
  if (i < n) out[i] = 0;
}

// ---- length counting sort: lperm = seq ids sorted by length ----
__global__ void k_lhist(const int* __restrict__ lengths, int* __restrict__ lcnt) {
  int i = blockIdx.x * 256 + threadIdx.x;
  if (i < NSEQ) atomicAdd(&lcnt[clampi(lengths[i], 1, TT) - 1], 1);
}
__global__ void k_lscan(const int* __restrict__ lcnt, int* __restrict__ lcur) {
  if (threadIdx.x == 0 && blockIdx.x == 0) {
    int run = 0;
    for (int i = 0; i < TT; ++i) { lcur[i] = run; run += lcnt[i]; }
  }
}
__global__ void k_lscatter(const int* __restrict__ lengths, int* __restrict__ lcur,
                           int* __restrict__ lperm) {
  int i = blockIdx.x * 256 + threadIdx.x;
  if (i < NSEQ) {
    int b = clampi(lengths[i], 1, TT) - 1;
    int pos = atomicAdd(&lcur[b], 1);
    lperm[clampi(pos, 0, NSEQ - 1)] = i;
  }
}

// ---------------------------------------------------------------------------
// Fused BiLSTM. Blocks take 64 length-sorted seqs (via lperm) and loop only to
// the block max length (~0.55*T avg). Ax AND Ah double-buffered -> ONE barrier
// per step; x(t+1) prefetch issued BEFORE the MFMA m-loop so its HBM latency
// hides behind compute instead of stalling at the barrier.
// ---------------------------------------------------------------------------
template<int BF>
__global__ __launch_bounds__(512, 2) void k_lstm(
    const void* __restrict__ x, const int* __restrict__ lengths,
    const int* __restrict__ lperm,
    const u16* __restrict__ canon, u16* __restrict__ hcat,
    const int* __restrict__ flag)
{
  if (flag[0] != BF) return;
  __shared__ u16 Ax[2][64 * 128];
  __shared__ u16 Ah[2][64 * 128];
  __shared__ int lenS[64];
  __shared__ int seqS[64];
  __shared__ int sMax;

  const int tid = threadIdx.x;
  const int wv = tid >> 6;
  const int lane = tid & 63;
  const int q = lane >> 4;
  const int cc = lane & 15;
  const int dir = blockIdx.y;
  const int b0 = blockIdx.x * 64;

  const u16* Wi = canon + (dir ? OFF_WIHB : OFF_WIHF);
  const u16* Wh = canon + (dir ? OFF_WHHB : OFF_WHHF);
  const u16* bb = canon + (dir ? OFF_BB : OFF_BF);

  // Weight B-fragments: B[k][n], n = lane&15 (gate column), k = q*8+j.
  bf16x8 wih[4][4], whh[4][4];
  float bv[4];
#pragma unroll
  for (int g = 0; g < 4; ++g) {
    int row = g * 128 + wv * 16 + cc;
#pragma unroll
    for (int kt = 0; kt < 4; ++kt) {
      wih[g][kt] = *(const bf16x8*)(Wi + row * 128 + kt * 32 + q * 8);
      whh[g][kt] = *(const bf16x8*)(Wh + row * 128 + kt * 32 + q * 8);
    }
    bv[g] = bf2f(bb[g * 128 + wv * 16 + cc]);
  }

  if (tid < 64) {
    int s = lperm[clampi(b0 + tid, 0, NSEQ - 1)];
    s = clampi(s, 0, NSEQ - 1);
    seqS[tid] = s;
    int L = clampi(lengths[s], 1, TT);
    lenS[tid] = L;
    // wave 0 reduce max
#pragma unroll
    for (int off = 32; off >= 1; off >>= 1) L = max(L, __shfl_xor(L, off, 64));
    if (tid == 0) sMax = L;
  }
  {
    f32x4 zz = {0.f, 0.f, 0.f, 0.f};
    f32x4* p = (f32x4*)Ah[0];
    for (int i = tid; i < 1024; i += 512) p[i] = zz;   // h0 = 0
  }
  __syncthreads();

  const int tmax = sMax;

  int lenp[4];
#pragma unroll
  for (int m = 0; m < 4; ++m) {
    int v = 0;
#pragma unroll
    for (int r = 0; r < 4; ++r) v |= lenS[m * 16 + q * 4 + r] << (8 * r);
    lenp[m] = v;
  }

  const int lrow = tid >> 3;
  const int lj = tid & 7;
  const int sL = seqS[lrow];
  const int lenL = lenS[lrow];
  const size_t xbase = (size_t)sL * (TT * FD);

  {  // stage x(0) into Ax[0]
    int t0 = dir ? (lenL - 1) : 0;
    bf16x8 d0 = ld8<BF>(x, xbase + t0 * FD + lj * 8);
    bf16x8 d1 = ld8<BF>(x, xbase + t0 * FD + (lj + 8) * 8);
    *(bf16x8*)&Ax[0][lrow * 128 + ((lj ^ (lrow & 15)) * 8)] = d0;
    *(bf16x8*)&Ax[0][lrow * 128 + (((lj + 8) ^ (lrow & 15)) * 8)] = d1;
  }
  float c[4][4] = {};
  int cb = 0;
  __syncthreads();

#pragma unroll 1
  for (int t = 0; t < tmax; ++t) {
    const u16* Axr = Ax[cb];
    u16* Axw = Ax[cb ^ 1];
    const u16* Ahr = Ah[cb];
    u16* Ahw = Ah[cb ^ 1];

    // issue x(t+1) prefetch FIRST: its latency hides behind the MFMA m-loop
    bf16x8 d0 = {}, d1 = {};
    const bool more = (t + 1 < tmax);
    if (more) {
      int tn = t + 1;
      int tt2 = dir ? (lenL - 1 - tn) : tn;
      if (tt2 < 0) tt2 = 0;
      d0 = ld8<BF>(x, xbase + tt2 * FD + lj * 8);
      d1 = ld8<BF>(x, xbase + tt2 * FD + (lj + 8) * 8);
    }

#pragma unroll
    for (int m = 0; m < 4; ++m) {
      f32x4 acc[4];
#pragma unroll
      for (int g = 0; g < 4; ++g) { f32x4 vi = {bv[g], bv[g], bv[g], bv[g]}; acc[g] = vi; }
      int row = m * 16 + cc;
#pragma unroll
      for (int kt = 0; kt < 4; ++kt) {
        bf16x8 a = *(const bf16x8*)&Axr[row * 128 + (((4 * kt + q) ^ (row & 15)) * 8)];
#pragma unroll
        for (int g = 0; g < 4; ++g)
          acc[g] = __builtin_amdgcn_mfma_f32_16x16x32_bf16(a, wih[g][kt], acc[g], 0, 0, 0);
      }
#pragma unroll
      for (int kt = 0; kt < 4; ++kt) {
        bf16x8 a = *(const bf16x8*)&Ahr[row * 128 + (((4 * kt + q) ^ (row & 15)) * 8)];
#pragma unroll
        for (int g = 0; g < 4; ++g)
          acc[g] = __builtin_amdgcn_mfma_f32_16x16x32_bf16(a, whh[g][kt], acc[g], 0, 0, 0);
      }

      // nonlinearity for this mtile; masked rows carry old h into Ahw
      int lp = lenp[m];
      int hu = wv * 16 + cc;
#pragma unroll
      for (int r = 0; r < 4; ++r) {
        int hrow = m * 16 + q * 4 + r;
        int cell = hrow * 128 + (((hu >> 3) ^ (hrow & 15)) * 8) + (hu & 7);
        u16 hv;
        if (t < ((lp >> (8 * r)) & 255)) {
          float iv = acc[0][r], fv = acc[1][r], gv = acc[2][r], ov = acc[3][r];
          float cn = sigm(fv) * c[m][r] + sigm(iv) * tanh_f(gv);
          c[m][r] = cn;
          hv = f2bf(sigm(ov) * tanh_f(cn));
        } else {
          hv = Ahr[cell];
        }
        Ahw[cell] = hv;
      }
    }

    // store prefetched x(t+1) into the OTHER Ax buffer (no reader this step)
    if (more) {
      *(bf16x8*)&Axw[lrow * 128 + ((lj ^ (lrow & 15)) * 8)] = d0;
      *(bf16x8*)&Axw[lrow * 128 + (((lj + 8) ^ (lrow & 15)) * 8)] = d1;
    }
    __syncthreads();   // single barrier per step
    cb ^= 1;
  }

  // epilogue: Ah[cb] holds last-valid h; write to hcat[seq, dir*128:+128]
  for (int i = tid; i < 1024; i += 512) {
    int row = i >> 4, ch = i & 15;
    if (b0 + row < NSEQ) {
      int seq = seqS[row];
      bf16x8 v = *(const bf16x8*)&Ah[cb][row * 128 + ((ch ^ (row & 15)) * 8)];
      *(bf16x8*)(hcat + (size_t)seq * 256 + dir * 128 + ch * 8) = v;
    }
  }
}

// ---------------------------------------------------------------------------
// Tiled bf16 GEMM: C[M,Nc] = A[M,K] * W[Nc,K]^T (A, W both ws-canonical bf16)
// ---------------------------------------------------------------------------
__global__ __launch_bounds__(256) void k_gemm(
    const u16* __restrict__ A, const u16* __restrict__ W, u16* __restrict__ C,
    int M, int Nc, int K)
{
  __shared__ u16 As[128 * 64];
  __shared__ u16 Bs[128 * 64];
  const int tid = threadIdx.x;
  const int wv = tid >> 6, lane = tid & 63, q = lane >> 4, cc = lane & 15;
  const int mblk = blockIdx.x * 128, nblk = blockIdx.y * 128;
  const int wm = (wv & 1) * 64, wn = (wv >> 1) * 64;

  f32x4 acc[4][4] = {};

  const int srow = tid >> 1;
  const int sc0 = (tid & 1) * 4;
  int arow_g = mblk + srow; if (arow_g > M - 1) arow_g = M - 1;
  const u16* aptr = A + (size_t)arow_g * K + sc0 * 8;
  const u16* bptr = W + (size_t)(nblk + srow) * K + sc0 * 8;

  for (int k0 = 0; k0 < K; k0 += 64) {
#pragma unroll
    for (int cch = 0; cch < 4; ++cch) {
      bf16x8 av = *(const bf16x8*)(aptr + k0 + cch * 8);
      bf16x8 bvv = *(const bf16x8*)(bptr + k0 + cch * 8);
      int ch = sc0 + cch;
      *(bf16x8*)&As[srow * 64 + ((ch ^ (srow & 7)) * 8)] = av;
      *(bf16x8*)&Bs[srow * 64 + ((ch ^ (srow & 7)) * 8)] = bvv;
    }
    __syncthreads();
#pragma unroll
    for (int kt = 0; kt < 2; ++kt) {
      bf16x8 af[4];
#pragma unroll
      for (int m = 0; m < 4; ++m) {
        int row = wm + m * 16 + cc;
        af[m] = *(const bf16x8*)&As[row * 64 + (((4 * kt + q) ^ (row & 7)) * 8)];
      }
#pragma unroll
      for (int n = 0; n < 4; ++n) {
        int rowb = wn + n * 16 + cc;
        bf16x8 bfr = *(const bf16x8*)&Bs[rowb * 64 + (((4 * kt + q) ^ (rowb & 7)) * 8)];
#pragma unroll
        for (int m = 0; m < 4; ++m)
          acc[m][n] = __builtin_amdgcn_mfma_f32_16x16x32_bf16(af[m], bfr, acc[m][n], 0, 0, 0);
      }
    }
    __syncthreads();
  }

#pragma unroll
  for (int m = 0; m < 4; ++m)
#pragma unroll
    for (int n = 0; n < 4; ++n)
#pragma unroll
      for (int r = 0; r < 4; ++r) {
        int row = mblk + wm + m * 16 + q * 4 + r;
        int col = nblk + wn + n * 16 + cc;
        if (row < M) C[(size_t)row * Nc + col] = f2bf(acc[m][n][r]);
      }
}

__global__ __launch_bounds__(256) void k_al1(
    const u16* __restrict__ xh1, const u16* __restrict__ canon,
    float* __restrict__ als, float* __restrict__ ald)
{
  const int lane = threadIdx.x & 63;
  const int n = blockIdx.x * 4 + (threadIdx.x >> 6);
  const int hd = lane >> 4;
  bf16x8 xv = *(const bf16x8*)(xh1 + (size_t)n * 512 + lane * 8);
  bf16x8 sv = *(const bf16x8*)(canon + OFF_A1S + hd * 128 + (lane & 15) * 8);
  bf16x8 dv = *(const bf16x8*)(canon + OFF_A1D + hd * 128 + (lane & 15) * 8);
  float ps = 0.f, pd = 0.f;
#pragma unroll
  for (int j = 0; j < 8; ++j) {
    float xf = bf2f((u16)xv[j]);
    ps += xf * bf2f((u16)sv[j]);
    pd += xf * bf2f((u16)dv[j]);
  }
#pragma unroll
  for (int off = 8; off >= 1; off >>= 1) {
    ps += __shfl_xor(ps, off, 64);
    pd += __shfl_xor(pd, off, 64);
  }
  if ((lane & 15) == 0) { als[n * 4 + hd] = ps; ald[n * 4 + hd] = pd; }
}

__global__ __launch_bounds__(256) void k_agg1(
    const u16* __restrict__ xh1, const float* __restrict__ als, const float* __restrict__ ald,
    const int* __restrict__ offs, const int* __restrict__ csr,
    const u16* __restrict__ canon, u16* __restrict__ h1)
{
  const int lane = threadIdx.x & 63;
  const int n = blockIdx.x * 4 + (threadIdx.x >> 6);
  int off0 = offs[n], off1 = offs[n + 1];
  off0 = clampi(off0, 0, ETOT);
  off1 = clampi(off1, off0, ETOT);
  float ad[4];
#pragma unroll
  for (int h = 0; h < 4; ++h) ad[h] = ald[(size_t)n * 4 + h];

  float mx[4] = {-1e30f, -1e30f, -1e30f, -1e30f};
  for (int k = off0 + lane; k < off1; k += 64) {
    int s = clampi(csr[k], 0, NSEQ - 1);
    float4 av = *(const float4*)(als + (size_t)s * 4);
    float ev[4] = {av.x, av.y, av.z, av.w};
#pragma unroll
    for (int h = 0; h < 4; ++h) {
      float e = ev[h] + ad[h];
      e = e > 0.f ? e : 0.2f * e;
      mx[h] = fmaxf(mx[h], e);
    }
  }
#pragma unroll
  for (int off = 32; off >= 1; off >>= 1)
#pragma unroll
    for (int h = 0; h < 4; ++h) mx[h] = fmaxf(mx[h], __shfl_xor(mx[h], off, 64));

  float sm[4] = {0.f, 0.f, 0.f, 0.f};
  for (int k = off0 + lane; k < off1; k += 64) {
    int s = clampi(csr[k], 0, NSEQ - 1);
    float4 av = *(const float4*)(als + (size_t)s * 4);
    float ev[4] = {av.x, av.y, av.z, av.w};
#pragma unroll
    for (int h = 0; h < 4; ++h) {
      float e = ev[h] + ad[h];
      e = e > 0.f ? e : 0.2f * e;
      sm[h] += __expf(e - mx[h]);
    }
  }
#pragma unroll
  for (int off = 32; off >= 1; off >>= 1)
#pragma unroll
    for (int h = 0; h < 4; ++h) sm[h] += __shfl_xor(sm[h], off, 64);
  float rd[4];
#pragma unroll
  for (int h = 0; h < 4; ++h) rd[h] = 1.0f / (sm[h] + 1e-16f);

  const int hd = lane >> 4;
  float o[8] = {};
  for (int k = off0; k < off1; ++k) {
    int s = clampi(csr[k], 0, NSEQ - 1);
    float e = als[(size_t)s * 4 + hd] + ad[hd];
    e = e > 0.f ? e : 0.2f * e;
    float a = __expf(e - mx[hd]) * rd[hd];
    bf16x8 xv = *(const bf16x8*)(xh1 + (size_t)s * 512 + lane * 8);
#pragma unroll
    for (int j = 0; j < 8; ++j) o[j] += a * bf2f((u16)xv[j]);
  }
  bf16x8 bvv = *(const bf16x8*)(canon + OFF_B1 + lane * 8);
  bf16x8 resv;
#pragma unroll
  for (int j = 0; j < 8; ++j) {
    float v = o[j] + bf2f((u16)bvv[j]);
    v = v > 0.f ? v : 0.f;
    resv[j] = (short)f2bf(v);
  }
  *(bf16x8*)(h1 + (size_t)n * 512 + lane * 8) = resv;
}

__global__ __launch_bounds__(256) void k_al2(
    const u16* __restrict__ xh2, const u16* __restrict__ canon,
    float* __restrict__ als2, float* __restrict__ ald2)
{
  const int lane = threadIdx.x & 63;
  const int n = blockIdx.x * 4 + (threadIdx.x >> 6);
  float x0 = bf2f(xh2[(size_t)n * 128 + lane * 2]);
  float x1 = bf2f(xh2[(size_t)n * 128 + lane * 2 + 1]);
  float ps = x0 * bf2f(canon[OFF_A2S + lane * 2]) + x1 * bf2f(canon[OFF_A2S + lane * 2 + 1]);
  float pd = x0 * bf2f(canon[OFF_A2D + lane * 2]) + x1 * bf2f(canon[OFF_A2D + lane * 2 + 1]);
#pragma unroll
  for (int off = 32; off >= 1; off >>= 1) {
    ps += __shfl_xor(ps, off, 64);
    pd += __shfl_xor(pd, off, 64);
  }
  if (lane == 0) { als2[n] = ps; ald2[n] = pd; }
}

__global__ __launch_bounds__(256) void k_agg2(
    const u16* __restrict__ xh2, const float* __restrict__ als2, const float* __restrict__ ald2,
    const int* __restrict__ offs, const int* __restrict__ csr,
    const u16* __restrict__ canon, float* __restrict__ h2)
{
  const int lane = threadIdx.x & 63;
  const int n = blockIdx.x * 4 + (threadIdx.x >> 6);
  int off0 = offs[n], off1 = offs[n + 1];
  off0 = clampi(off0, 0, ETOT);
  off1 = clampi(off1, off0, ETOT);
  const float adn = ald2[n];

  float mx = -1e30f;
  for (int k = off0 + lane; k < off1; k += 64) {
    float e = als2[clampi(csr[k], 0, NSEQ - 1)] + adn;
    e = e > 0.f ? e : 0.2f * e;
    mx = fmaxf(mx, e);
  }
#pragma unroll
  for (int off = 32; off >= 1; off >>= 1) mx = fmaxf(mx, __shfl_xor(mx, off, 64));
  float sm = 0.f;
  for (int k = off0 + lane; k < off1; k += 64) {
    float e = als2[clampi(csr[k], 0, NSEQ - 1)] + adn;
    e = e > 0.f ? e : 0.2f * e;
    sm += __expf(e - mx);
  }
#pragma unroll
  for (int off = 32; off >= 1; off >>= 1) sm += __shfl_xor(sm, off, 64);
  float rd = 1.0f / (sm + 1e-16f);

  float o0 = 0.f, o1 = 0.f;
  for (int k = off0; k < off1; ++k) {
    int s = clampi(csr[k], 0, NSEQ - 1);
    float e = als2[s] + adn;
    e = e > 0.f ? e : 0.2f * e;
    float a = __expf(e - mx) * rd;
    u32 xv = *(const u32*)(xh2 + (size_t)s * 128 + lane * 2);
    o0 += a * bf2f((u16)(xv & 0xffffu));
    o1 += a * bf2f((u16)(xv >> 16));
  }
  o0 += bf2f(canon[OFF_B2 + lane * 2]);     o0 = o0 > 0.f ? o0 : 0.f;
  o1 += bf2f(canon[OFF_B2 + lane * 2 + 1]); o1 = o1 > 0.f ? o1 : 0.f;
  float2 st; st.x = o0; st.y = o1;
  *(float2*)(h2 + (size_t)n * 128 + lane * 2) = st;
}

template<int BF>
__global__ __launch_bounds__(256) void k_fc(
    const float* __restrict__ h2, const u16* __restrict__ canon,
    void* __restrict__ out, const int* __restrict__ flag)
{
  if (flag[0] != BF) return;
  const int lane = threadIdx.x & 63;
  const int n = blockIdx.x * 4 + (threadIdx.x >> 6);
  float a0 = h2[(size_t)n * 128 + lane];
  float a1 = h2[(size_t)n * 128 + 64 + lane];
  float res[10];
#pragma unroll
  for (int cls = 0; cls < 10; ++cls) {
    float p = a0 * bf2f(canon[OFF_WFC + cls * 128 + lane]) +
              a1 * bf2f(canon[OFF_WFC + cls * 128 + 64 + lane]);
#pragma unroll
    for (int off = 32; off >= 1; off >>= 1) p += __shfl_xor(p, off, 64);
    float v = p + bf2f(canon[OFF_BFC + cls]);
    res[cls] = (fabsf(v) < 1e30f) ? v : 0.f;
  }
  if (BF) {
    if (lane < 5) {
      u32 pk = (u32)f2bf(res[lane * 2]) | ((u32)f2bf(res[lane * 2 + 1]) << 16);
      ((u32*)out)[(size_t)n * 5 + lane] = pk;
    }
  } else {
    if (lane < 10) ((float*)out)[(size_t)n * 10 + lane] = res[lane];
  }
}

// ---- CSR build ----
__global__ void k_zero(int* __restrict__ p, int cnt) {
  int i = blockIdx.x * 256 + threadIdx.x;
  if (i < cnt) p[i] = 0;
}

__global__ void k_hist(const int* __restrict__ ei, int* __restrict__ deg) {
  int i = blockIdx.x * 256 + threadIdx.x;
  if (i < ETOT) {
    int d = (i < EDG) ? ei[EDG + i] : (i - EDG);
    d = clampi(d, 0, NSEQ - 1);
    atomicAdd(&deg[d], 1);
  }
}

// single-block exclusive scan: 20 elems/thread serial + wave shuffle scan +
// 16-entry LDS cross-wave combine
__global__ __launch_bounds__(1024) void k_scan(const int* __restrict__ deg,
                                               int* __restrict__ offs, int* __restrict__ cur) {
  __shared__ int wsum[16];
  const int tid = threadIdx.x;
  const int lane = tid & 63, wv = tid >> 6;
  const int CHUNK = 20;
  int base = tid * CHUNK;
  int loc[20];
  int s = 0;
#pragma unroll
  for (int i = 0; i < CHUNK; ++i) {
    int idx = base + i;
    int v = (idx < NSEQ) ? deg[idx] : 0;
    loc[i] = s;
    s += v;
  }
  int inc = s;
#pragma unroll
  for (int off = 1; off < 64; off <<= 1) {
    int t2 = __shfl_up(inc, off, 64);
    if (lane >= off) inc += t2;
  }
  if (lane == 63) wsum[wv] = inc;
  __syncthreads();
  int wbase = 0;
  for (int i = 0; i < wv; ++i) wbase += wsum[i];
  int tbase = wbase + inc - s;
#pragma unroll
  for (int i = 0; i < CHUNK; ++i) {
    int idx = base + i;
    if (idx < NSEQ) {
      int st = tbase + loc[i];
      offs[idx] = st;
      cur[idx] = st;
    }
  }
  if (tid == 0) offs[NSEQ] = ETOT;
}

__global__ void k_scatter(const int* __restrict__ ei, int* __restrict__ cur,
                          int* __restrict__ csr) {
  int i = blockIdx.x * 256 + threadIdx.x;
  if (i < ETOT) {
    int s, d;
    if (i < EDG) { s = ei[i]; d = ei[EDG + i]; }
    else { s = i - EDG; d = s; }
    d = clampi(d, 0, NSEQ - 1);
    int pos = atomicAdd(&cur[d], 1);
    pos = clampi(pos, 0, ETOT - 1);
    csr[pos] = s;
  }
}

extern "C" void kernel_launch(void* const* d_in, const int* in_sizes, int n_in,
                              void* d_out, int out_size, void* d_ws, size_t ws_size,
                              hipStream_t stream) {
  (void)in_sizes; (void)n_in;
  const void* x     = d_in[0];
  const int* lengths= (const int*)d_in[1];
  const int* ei     = (const int*)d_in[2];

  const size_t NEED = 45769344u;
  if (ws_size < NEED) {
    k_fill0<<<(out_size + 255) / 256, 256, 0, stream>>>((u16*)d_out, out_size);
    return;
  }

  char* w = (char*)d_ws;
  size_t o = 0;
  auto alloc = [&](size_t b) { char* p = w + o; o += (b + 255) & ~(size_t)255; return p; };
  int*  flag = (int*)  alloc(256);
  u16*  canon= (u16*)  alloc(1048576);
  int*  deg  = (int*)  alloc((size_t)NSEQ * 4);
  int*  offs = (int*)  alloc((size_t)(NSEQ + 1) * 4);
  int*  cur  = (int*)  alloc((size_t)NSEQ * 4);
  int*  csr  = (int*)  alloc((size_t)ETOT * 4);
  float* als1= (float*)alloc((size_t)NSEQ * 4 * 4);
  float* ald1= (float*)alloc((size_t)NSEQ * 4 * 4);
  char* regB = alloc((size_t)NSEQ * 512 * 2);            // xh1 / later xh2,h2,als2,ald2
  u16*  xh1  = (u16*)regB;
  u16*  xh2  = (u16*)regB;
  float* h2  = (float*)(regB + (size_t)NSEQ * 128 * 2);
  float* als2= (float*)(regB + (size_t)NSEQ * 128 * 2 + (size_t)NSEQ * 128 * 4);
  float* ald2= als2 + NSEQ;
  char* regA = alloc((size_t)NSEQ * 256 * 2);            // hcat / later h1 (w/ ext)
  u16*  hcat = (u16*)regA;
  u16*  h1   = (u16*)regA;
  alloc((size_t)NSEQ * 256 * 2);                         // h1 extension

  // length-sort scratch lives in regB (dead until k_gemm #1, which runs
  // after k_lstm has consumed lperm)
  int* lperm = (int*)regB;                       // 80000 B
  int* lcnt  = (int*)(regB + 80128);             // 32 ints
  int* lcur  = (int*)(regB + 80256);             // 32 ints

  k_detect<<<1, 64, 0, stream>>>((const u32*)x, flag);
  CvtArgs ca;
  const int srcIdx[16] = {3, 4, 5, 6, 7, 8, 9, 13, 10, 11, 12, 14, 15, 16, 17, 18};
  const int offv[16]   = {OFF_WIHF, OFF_WHHF, OFF_BF, OFF_WIHB, OFF_WHHB, OFF_BB,
                          OFF_W1, OFF_W2, OFF_A1S, OFF_A1D, OFF_B1,
                          OFF_A2S, OFF_A2D, OFF_B2, OFF_WFC, OFF_BFC};
  const int cntv[16]   = {65536, 65536, 512, 65536, 65536, 512,
                          131072, 65536, 512, 512, 512, 128, 128, 128, 1280, 10};
  for (int i = 0; i < 16; ++i) { ca.src[i] = d_in[srcIdx[i]]; ca.off[i] = offv[i]; ca.cnt[i] = cntv[i]; }
  k_cvt<1><<<256, 256, 0, stream>>>(ca, canon, flag);
  k_cvt<0><<<256, 256, 0, stream>>>(ca, canon, flag);

  // length counting-sort -> lperm
  k_zero<<<1, 256, 0, stream>>>(lcnt, 64);
  k_lhist<<<(NSEQ + 255) / 256, 256, 0, stream>>>(lengths, lcnt);
  k_lscan<<<1, 64, 0, stream>>>(lcnt, lcur);
  k_lscatter<<<(NSEQ + 255) / 256, 256, 0, stream>>>(lengths, lcur, lperm);

  // CSR build
  k_zero<<<(NSEQ + 255) / 256, 256, 0, stream>>>(deg, NSEQ);
  k_hist<<<(ETOT + 255) / 256, 256, 0, stream>>>(ei, deg);
  k_scan<<<1, 1024, 0, stream>>>(deg, offs, cur);
  k_scatter<<<(ETOT + 255) / 256, 256, 0, stream>>>(ei, cur, csr);

  k_lstm<1><<<dim3(313, 2), 512, 0, stream>>>(x, lengths, lperm, canon, hcat, flag);
  k_lstm<0><<<dim3(313, 2), 512, 0, stream>>>(x, lengths, lperm, canon, hcat, flag);

  k_gemm<<<dim3(157, 4), 256, 0, stream>>>(hcat, canon + OFF_W1, xh1, NSEQ, 512, 256);
  k_al1<<<5000, 256, 0, stream>>>(xh1, canon, als1, ald1);
  k_agg1<<<5000, 256, 0, stream>>>(xh1, als1, ald1, offs, csr, canon, h1);

  k_gemm<<<dim3(157, 1), 256, 0, stream>>>(h1, canon + OFF_W2, xh2, NSEQ, 128, 512);
  k_al2<<<5000, 256, 0, stream>>>(xh2, canon, als2, ald2);
  k_agg2<<<5000, 256, 0, stream>>>(xh2, als2, ald2, offs, csr, canon, h2);

  k_fc<1><<<5000, 256, 0, stream>>>(h2, canon, d_out, flag);
  k_fc<0><<<5000, 256, 0, stream>>>(h2, canon, d_out, flag);
}

// Round 6
// 1023.655 us; speedup vs baseline: 1.0083x; 1.0083x over previous
//
#include <hip/hip_runtime.h>

#define NSEQ 20000
#define TT 20
#define FD 128
#define EDG 640000
#define ETOT (EDG + NSEQ)

typedef short bf16x8 __attribute__((ext_vector_type(8)));
typedef float f32x4 __attribute__((ext_vector_type(4)));
typedef unsigned short u16;
typedef unsigned int u32;

__device__ __forceinline__ float bf2f(u16 h) {
  union { u32 u; float f; } v; v.u = ((u32)h) << 16; return v.f;
}
__device__ __forceinline__ u16 f2bf(float f) {
  union { float f; u32 u; } v; v.f = f;
  u32 u = v.u;
  return (u16)((u + 0x7fffu + ((u >> 16) & 1u)) >> 16);
}
__device__ __forceinline__ float sigm(float x) { return 1.0f / (1.0f + __expf(-x)); }
__device__ __forceinline__ float tanh_f(float x) { return 1.0f - 2.0f / (__expf(2.0f * x) + 1.0f); }
__device__ __forceinline__ int clampi(int v, int lo, int hi) {
  return v < lo ? lo : (v > hi ? hi : v);
}

// generic loaders over raw input (BF=1: bf16, BF=0: fp32)
template<int BF>
__device__ __forceinline__ bf16x8 ld8(const void* p, size_t i) {
  if (BF) return *(const bf16x8*)((const u16*)p + i);
  f32x4 a = *(const f32x4*)((const float*)p + i);
  f32x4 b = *(const f32x4*)((const float*)p + i + 4);
  bf16x8 r;
  r[0] = (short)f2bf(a[0]); r[1] = (short)f2bf(a[1]);
  r[2] = (short)f2bf(a[2]); r[3] = (short)f2bf(a[3]);
  r[4] = (short)f2bf(b[0]); r[5] = (short)f2bf(b[1]);
  r[6] = (short)f2bf(b[2]); r[7] = (short)f2bf(b[3]);
  return r;
}

// canonical-weights element offsets (u16 units) inside the canon block
#define OFF_WIHF 0
#define OFF_WHHF 65536
#define OFF_BF   131072
#define OFF_WIHB 131584
#define OFF_WHHB 197120
#define OFF_BB   262656
#define OFF_W1   263168
#define OFF_W2   394240
#define OFF_A1S  459776
#define OFF_A1D  460288
#define OFF_B1   460800
#define OFF_A2S  461312
#define OFF_A2D  461440
#define OFF_B2   461568
#define OFF_WFC  461696
#define OFF_BFC  462976

// parallel dtype detector: low16 of fp32 words have random exponent fields
__global__ void k_detect(const u32* __restrict__ xw, int* __restrict__ flag) {
  const int lane = threadIdx.x & 63;
  u16 lo = (u16)(xw[lane] & 0xffffu);
  int e = (lo >> 7) & 0xff;
  unsigned long long m = __ballot(e >= 100 && e <= 140);
  if (threadIdx.x == 0) flag[0] = (__popcll(m) >= 32) ? 1 : 0;
}

struct CvtArgs {
  const void* src[16];
  int off[16];
  int cnt[16];
};

template<int BF>
__global__ void k_cvt(CvtArgs a, u16* __restrict__ canon, const int* __restrict__ flag) {
  if (flag[0] != BF) return;
  int idx = blockIdx.x * 256 + threadIdx.x;
  int stride = gridDim.x * 256;
#pragma unroll 1
  for (int s = 0; s < 16; ++s) {
    const void* sp = a.src[s];
    int n = a.cnt[s], off = a.off[s];
    for (int i = idx; i < n; i += stride) {
      canon[off + i] = BF ? ((const u16*)sp)[i] : f2bf(((const float*)sp)[i]);
    }
  }
}

__global__ void k_fill0(u16* __restrict__ out, int n) {
  int i = blockIdx.x * 256 + threadIdx.x;
  if (i < n) out[i] = 0;
}

// ---- length counting sort: lperm = seq ids sorted by length ----
__global__ void k_lhist(const int* __restrict__ lengths, int* __restrict__ lcnt) {
  int i = blockIdx.x * 256 + threadIdx.x;
  if (i < NSEQ) atomicAdd(&lcnt[clampi(lengths[i], 1, TT) - 1], 1);
}
__global__ void k_lscan(const int* __restrict__ lcnt, int* __restrict__ lcur) {
  if (threadIdx.x == 0 && blockIdx.x == 0) {
    int run = 0;
    for (int i = 0; i < TT; ++i) { lcur[i] = run; run += lcnt[i]; }
  }
}
__global__ void k_lscatter(const int* __restrict__ lengths, int* __restrict__ lcur,
                           int* __restrict__ lperm) {
  int i = blockIdx.x * 256 + threadIdx.x;
  if (i < NSEQ) {
    int b = clampi(lengths[i], 1, TT) - 1;
    int pos = atomicAdd(&lcur[b], 1);
    lperm[clampi(pos, 0, NSEQ - 1)] = i;
  }
}

// ---------------------------------------------------------------------------
// Fused BiLSTM. Blocks take 64 length-sorted seqs; LONGEST blocks dispatch
// FIRST (LPT packing: short blocks fill the tail). One barrier per step via
// double-buffered Ax/Ah; x(t+1) prefetch issued before the MFMA m-loop.
// ---------------------------------------------------------------------------
template<int BF>
__global__ __launch_bounds__(512, 2) void k_lstm(
    const void* __restrict__ x, const int* __restrict__ lengths,
    const int* __restrict__ lperm,
    const u16* __restrict__ canon, u16* __restrict__ hcat,
    const int* __restrict__ flag)
{
  if (flag[0] != BF) return;
  __shared__ u16 Ax[2][64 * 128];
  __shared__ u16 Ah[2][64 * 128];
  __shared__ int lenS[64];
  __shared__ int seqS[64];
  __shared__ int sMax;

  const int tid = threadIdx.x;
  const int wv = tid >> 6;
  const int lane = tid & 63;
  const int q = lane >> 4;
  const int cc = lane & 15;
  const int dir = blockIdx.y;
  // longest-first: lperm ascending, so reverse the block order
  const int b0 = (gridDim.x - 1 - blockIdx.x) * 64;

  const u16* Wi = canon + (dir ? OFF_WIHB : OFF_WIHF);
  const u16* Wh = canon + (dir ? OFF_WHHB : OFF_WHHF);
  const u16* bb = canon + (dir ? OFF_BB : OFF_BF);

  // Weight B-fragments: B[k][n], n = lane&15 (gate column), k = q*8+j.
  bf16x8 wih[4][4], whh[4][4];
  float bv[4];
#pragma unroll
  for (int g = 0; g < 4; ++g) {
    int row = g * 128 + wv * 16 + cc;
#pragma unroll
    for (int kt = 0; kt < 4; ++kt) {
      wih[g][kt] = *(const bf16x8*)(Wi + row * 128 + kt * 32 + q * 8);
      whh[g][kt] = *(const bf16x8*)(Wh + row * 128 + kt * 32 + q * 8);
    }
    bv[g] = bf2f(bb[g * 128 + wv * 16 + cc]);
  }

  if (tid < 64) {
    int s = lperm[clampi(b0 + tid, 0, NSEQ - 1)];
    s = clampi(s, 0, NSEQ - 1);
    seqS[tid] = s;
    int L = clampi(lengths[s], 1, TT);
    lenS[tid] = L;
#pragma unroll
    for (int off = 32; off >= 1; off >>= 1) L = max(L, __shfl_xor(L, off, 64));
    if (tid == 0) sMax = L;
  }
  {
    f32x4 zz = {0.f, 0.f, 0.f, 0.f};
    f32x4* p = (f32x4*)Ah[0];
    for (int i = tid; i < 1024; i += 512) p[i] = zz;   // h0 = 0
  }
  __syncthreads();

  const int tmax = sMax;

  int lenp[4];
#pragma unroll
  for (int m = 0; m < 4; ++m) {
    int v = 0;
#pragma unroll
    for (int r = 0; r < 4; ++r) v |= lenS[m * 16 + q * 4 + r] << (8 * r);
    lenp[m] = v;
  }

  const int lrow = tid >> 3;
  const int lj = tid & 7;
  const int sL = seqS[lrow];
  const int lenL = lenS[lrow];
  const size_t xbase = (size_t)sL * (TT * FD);

  {  // stage x(0) into Ax[0]
    int t0 = dir ? (lenL - 1) : 0;
    bf16x8 d0 = ld8<BF>(x, xbase + t0 * FD + lj * 8);
    bf16x8 d1 = ld8<BF>(x, xbase + t0 * FD + (lj + 8) * 8);
    *(bf16x8*)&Ax[0][lrow * 128 + ((lj ^ (lrow & 15)) * 8)] = d0;
    *(bf16x8*)&Ax[0][lrow * 128 + (((lj + 8) ^ (lrow & 15)) * 8)] = d1;
  }
  float c[4][4] = {};
  int cb = 0;
  __syncthreads();

#pragma unroll 1
  for (int t = 0; t < tmax; ++t) {
    const u16* Axr = Ax[cb];
    u16* Axw = Ax[cb ^ 1];
    const u16* Ahr = Ah[cb];
    u16* Ahw = Ah[cb ^ 1];

    // issue x(t+1) prefetch FIRST: its latency hides behind the MFMA m-loop
    bf16x8 d0 = {}, d1 = {};
    const bool more = (t + 1 < tmax);
    if (more) {
      int tn = t + 1;
      int tt2 = dir ? (lenL - 1 - tn) : tn;
      if (tt2 < 0) tt2 = 0;
      d0 = ld8<BF>(x, xbase + tt2 * FD + lj * 8);
      d1 = ld8<BF>(x, xbase + tt2 * FD + (lj + 8) * 8);
    }

#pragma unroll
    for (int m = 0; m < 4; ++m) {
      f32x4 acc[4];
#pragma unroll
      for (int g = 0; g < 4; ++g) { f32x4 vi = {bv[g], bv[g], bv[g], bv[g]}; acc[g] = vi; }
      int row = m * 16 + cc;
#pragma unroll
      for (int kt = 0; kt < 4; ++kt) {
        bf16x8 a = *(const bf16x8*)&Axr[row * 128 + (((4 * kt + q) ^ (row & 15)) * 8)];
#pragma unroll
        for (int g = 0; g < 4; ++g)
          acc[g] = __builtin_amdgcn_mfma_f32_16x16x32_bf16(a, wih[g][kt], acc[g], 0, 0, 0);
      }
#pragma unroll
      for (int kt = 0; kt < 4; ++kt) {
        bf16x8 a = *(const bf16x8*)&Ahr[row * 128 + (((4 * kt + q) ^ (row & 15)) * 8)];
#pragma unroll
        for (int g = 0; g < 4; ++g)
          acc[g] = __builtin_amdgcn_mfma_f32_16x16x32_bf16(a, whh[g][kt], acc[g], 0, 0, 0);
      }

      // nonlinearity for this mtile; masked rows carry old h into Ahw
      int lp = lenp[m];
      int hu = wv * 16 + cc;
#pragma unroll
      for (int r = 0; r < 4; ++r) {
        int hrow = m * 16 + q * 4 + r;
        int cell = hrow * 128 + (((hu >> 3) ^ (hrow & 15)) * 8) + (hu & 7);
        u16 hv;
        if (t < ((lp >> (8 * r)) & 255)) {
          float iv = acc[0][r], fv = acc[1][r], gv = acc[2][r], ov = acc[3][r];
          float cn = sigm(fv) * c[m][r] + sigm(iv) * tanh_f(gv);
          c[m][r] = cn;
          hv = f2bf(sigm(ov) * tanh_f(cn));
        } else {
          hv = Ahr[cell];
        }
        Ahw[cell] = hv;
      }
    }

    // store prefetched x(t+1) into the OTHER Ax buffer (no reader this step)
    if (more) {
      *(bf16x8*)&Axw[lrow * 128 + ((lj ^ (lrow & 15)) * 8)] = d0;
      *(bf16x8*)&Axw[lrow * 128 + (((lj + 8) ^ (lrow & 15)) * 8)] = d1;
    }
    __syncthreads();   // single barrier per step
    cb ^= 1;
  }

  // epilogue: Ah[cb] holds last-valid h; write to hcat[seq, dir*128:+128]
  for (int i = tid; i < 1024; i += 512) {
    int row = i >> 4, ch = i & 15;
    if (b0 + row < NSEQ) {
      int seq = seqS[row];
      bf16x8 v = *(const bf16x8*)&Ah[cb][row * 128 + ((ch ^ (row & 15)) * 8)];
      *(bf16x8*)(hcat + (size_t)seq * 256 + dir * 128 + ch * 8) = v;
    }
  }
}

// ---------------------------------------------------------------------------
// Tiled bf16 GEMM: C[M,Nc] = A[M,K] * W[Nc,K]^T (A, W both ws-canonical bf16)
// ---------------------------------------------------------------------------
__global__ __launch_bounds__(256) void k_gemm(
    const u16* __restrict__ A, const u16* __restrict__ W, u16* __restrict__ C,
    int M, int Nc, int K)
{
  __shared__ u16 As[128 * 64];
  __shared__ u16 Bs[128 * 64];
  const int tid = threadIdx.x;
  const int wv = tid >> 6, lane = tid & 63, q = lane >> 4, cc = lane & 15;
  const int mblk = blockIdx.x * 128, nblk = blockIdx.y * 128;
  const int wm = (wv & 1) * 64, wn = (wv >> 1) * 64;

  f32x4 acc[4][4] = {};

  const int srow = tid >> 1;
  const int sc0 = (tid & 1) * 4;
  int arow_g = mblk + srow; if (arow_g > M - 1) arow_g = M - 1;
  const u16* aptr = A + (size_t)arow_g * K + sc0 * 8;
  const u16* bptr = W + (size_t)(nblk + srow) * K + sc0 * 8;

  for (int k0 = 0; k0 < K; k0 += 64) {
#pragma unroll
    for (int cch = 0; cch < 4; ++cch) {
      bf16x8 av = *(const bf16x8*)(aptr + k0 + cch * 8);
      bf16x8 bvv = *(const bf16x8*)(bptr + k0 + cch * 8);
      int ch = sc0 + cch;
      *(bf16x8*)&As[srow * 64 + ((ch ^ (srow & 7)) * 8)] = av;
      *(bf16x8*)&Bs[srow * 64 + ((ch ^ (srow & 7)) * 8)] = bvv;
    }
    __syncthreads();
#pragma unroll
    for (int kt = 0; kt < 2; ++kt) {
      bf16x8 af[4];
#pragma unroll
      for (int m = 0; m < 4; ++m) {
        int row = wm + m * 16 + cc;
        af[m] = *(const bf16x8*)&As[row * 64 + (((4 * kt + q) ^ (row & 7)) * 8)];
      }
#pragma unroll
      for (int n = 0; n < 4; ++n) {
        int rowb = wn + n * 16 + cc;
        bf16x8 bfr = *(const bf16x8*)&Bs[rowb * 64 + (((4 * kt + q) ^ (rowb & 7)) * 8)];
#pragma unroll
        for (int m = 0; m < 4; ++m)
          acc[m][n] = __builtin_amdgcn_mfma_f32_16x16x32_bf16(af[m], bfr, acc[m][n], 0, 0, 0);
      }
    }
    __syncthreads();
  }

#pragma unroll
  for (int m = 0; m < 4; ++m)
#pragma unroll
    for (int n = 0; n < 4; ++n)
#pragma unroll
      for (int r = 0; r < 4; ++r) {
        int row = mblk + wm + m * 16 + q * 4 + r;
        int col = nblk + wn + n * 16 + cc;
        if (row < M) C[(size_t)row * Nc + col] = f2bf(acc[m][n][r]);
      }
}

__global__ __launch_bounds__(256) void k_al1(
    const u16* __restrict__ xh1, const u16* __restrict__ canon,
    float* __restrict__ als, float* __restrict__ ald)
{
  const int lane = threadIdx.x & 63;
  const int n = blockIdx.x * 4 + (threadIdx.x >> 6);
  const int hd = lane >> 4;
  bf16x8 xv = *(const bf16x8*)(xh1 + (size_t)n * 512 + lane * 8);
  bf16x8 sv = *(const bf16x8*)(canon + OFF_A1S + hd * 128 + (lane & 15) * 8);
  bf16x8 dv = *(const bf16x8*)(canon + OFF_A1D + hd * 128 + (lane & 15) * 8);
  float ps = 0.f, pd = 0.f;
#pragma unroll
  for (int j = 0; j < 8; ++j) {
    float xf = bf2f((u16)xv[j]);
    ps += xf * bf2f((u16)sv[j]);
    pd += xf * bf2f((u16)dv[j]);
  }
#pragma unroll
  for (int off = 8; off >= 1; off >>= 1) {
    ps += __shfl_xor(ps, off, 64);
    pd += __shfl_xor(pd, off, 64);
  }
  if ((lane & 15) == 0) { als[n * 4 + hd] = ps; ald[n * 4 + hd] = pd; }
}

// GAT layer-1 softmax + aggregation: one block per node, one WAVE per head.
// Lane covers 2 feats (u32 load = 256 B coalesced per wave per edge).
__global__ __launch_bounds__(256) void k_agg1(
    const u16* __restrict__ xh1, const float* __restrict__ als, const float* __restrict__ ald,
    const int* __restrict__ offs, const int* __restrict__ csr,
    const u16* __restrict__ canon, u16* __restrict__ h1)
{
  const int lane = threadIdx.x & 63;
  const int hd = threadIdx.x >> 6;
  const int n = blockIdx.x;
  int off0 = offs[n], off1 = offs[n + 1];
  off0 = clampi(off0, 0, ETOT);
  off1 = clampi(off1, off0, ETOT);
  const float ad = ald[(size_t)n * 4 + hd];

  float mx = -1e30f;
  for (int k = off0 + lane; k < off1; k += 64) {
    int s = clampi(csr[k], 0, NSEQ - 1);
    float e = als[(size_t)s * 4 + hd] + ad;
    e = e > 0.f ? e : 0.2f * e;
    mx = fmaxf(mx, e);
  }
#pragma unroll
  for (int off = 32; off >= 1; off >>= 1) mx = fmaxf(mx, __shfl_xor(mx, off, 64));

  float sm = 0.f;
  for (int k = off0 + lane; k < off1; k += 64) {
    int s = clampi(csr[k], 0, NSEQ - 1);
    float e = als[(size_t)s * 4 + hd] + ad;
    e = e > 0.f ? e : 0.2f * e;
    sm += __expf(e - mx);
  }
#pragma unroll
  for (int off = 32; off >= 1; off >>= 1) sm += __shfl_xor(sm, off, 64);
  const float rd = 1.0f / (sm + 1e-16f);

  float o0 = 0.f, o1 = 0.f;
  const u16* xb = xh1 + hd * 128 + lane * 2;
  for (int k = off0; k < off1; ++k) {
    int s = clampi(csr[k], 0, NSEQ - 1);
    float e = als[(size_t)s * 4 + hd] + ad;
    e = e > 0.f ? e : 0.2f * e;
    float a = __expf(e - mx) * rd;
    u32 xv = *(const u32*)(xb + (size_t)s * 512);
    o0 += a * bf2f((u16)(xv & 0xffffu));
    o1 += a * bf2f((u16)(xv >> 16));
  }
  o0 += bf2f(canon[OFF_B1 + hd * 128 + lane * 2]);
  o1 += bf2f(canon[OFF_B1 + hd * 128 + lane * 2 + 1]);
  o0 = o0 > 0.f ? o0 : 0.f;
  o1 = o1 > 0.f ? o1 : 0.f;
  u32 pk = (u32)f2bf(o0) | ((u32)f2bf(o1) << 16);
  *(u32*)(h1 + (size_t)n * 512 + hd * 128 + lane * 2) = pk;
}

__global__ __launch_bounds__(256) void k_al2(
    const u16* __restrict__ xh2, const u16* __restrict__ canon,
    float* __restrict__ als2, float* __restrict__ ald2)
{
  const int lane = threadIdx.x & 63;
  const int n = blockIdx.x * 4 + (threadIdx.x >> 6);
  float x0 = bf2f(xh2[(size_t)n * 128 + lane * 2]);
  float x1 = bf2f(xh2[(size_t)n * 128 + lane * 2 + 1]);
  float ps = x0 * bf2f(canon[OFF_A2S + lane * 2]) + x1 * bf2f(canon[OFF_A2S + lane * 2 + 1]);
  float pd = x0 * bf2f(canon[OFF_A2D + lane * 2]) + x1 * bf2f(canon[OFF_A2D + lane * 2 + 1]);
#pragma unroll
  for (int off = 32; off >= 1; off >>= 1) {
    ps += __shfl_xor(ps, off, 64);
    pd += __shfl_xor(pd, off, 64);
  }
  if (lane == 0) { als2[n] = ps; ald2[n] = pd; }
}

__global__ __launch_bounds__(256) void k_agg2(
    const u16* __restrict__ xh2, const float* __restrict__ als2, const float* __restrict__ ald2,
    const int* __restrict__ offs, const int* __restrict__ csr,
    const u16* __restrict__ canon, float* __restrict__ h2)
{
  const int lane = threadIdx.x & 63;
  const int n = blockIdx.x * 4 + (threadIdx.x >> 6);
  int off0 = offs[n], off1 = offs[n + 1];
  off0 = clampi(off0, 0, ETOT);
  off1 = clampi(off1, off0, ETOT);
  const float adn = ald2[n];

  float mx = -1e30f;
  for (int k = off0 + lane; k < off1; k += 64) {
    float e = als2[clampi(csr[k], 0, NSEQ - 1)] + adn;
    e = e > 0.f ? e : 0.2f * e;
    mx = fmaxf(mx, e);
  }
#pragma unroll
  for (int off = 32; off >= 1; off >>= 1) mx = fmaxf(mx, __shfl_xor(mx, off, 64));
  float sm = 0.f;
  for (int k = off0 + lane; k < off1; k += 64) {
    float e = als2[clampi(csr[k], 0, NSEQ - 1)] + adn;
    e = e > 0.f ? e : 0.2f * e;
    sm += __expf(e - mx);
  }
#pragma unroll
  for (int off = 32; off >= 1; off >>= 1) sm += __shfl_xor(sm, off, 64);
  float rd = 1.0f / (sm + 1e-16f);

  float o0 = 0.f, o1 = 0.f;
  for (int k = off0; k < off1; ++k) {
    int s = clampi(csr[k], 0, NSEQ - 1);
    float e = als2[s] + adn;
    e = e > 0.f ? e : 0.2f * e;
    float a = __expf(e - mx) * rd;
    u32 xv = *(const u32*)(xh2 + (size_t)s * 128 + lane * 2);
    o0 += a * bf2f((u16)(xv & 0xffffu));
    o1 += a * bf2f((u16)(xv >> 16));
  }
  o0 += bf2f(canon[OFF_B2 + lane * 2]);     o0 = o0 > 0.f ? o0 : 0.f;
  o1 += bf2f(canon[OFF_B2 + lane * 2 + 1]); o1 = o1 > 0.f ? o1 : 0.f;
  float2 st; st.x = o0; st.y = o1;
  *(float2*)(h2 + (size_t)n * 128 + lane * 2) = st;
}

template<int BF>
__global__ __launch_bounds__(256) void k_fc(
    const float* __restrict__ h2, const u16* __restrict__ canon,
    void* __restrict__ out, const int* __restrict__ flag)
{
  if (flag[0] != BF) return;
  const int lane = threadIdx.x & 63;
  const int n = blockIdx.x * 4 + (threadIdx.x >> 6);
  float a0 = h2[(size_t)n * 128 + lane];
  float a1 = h2[(size_t)n * 128 + 64 + lane];
  float res[10];
#pragma unroll
  for (int cls = 0; cls < 10; ++cls) {
    float p = a0 * bf2f(canon[OFF_WFC + cls * 128 + lane]) +
              a1 * bf2f(canon[OFF_WFC + cls * 128 + 64 + lane]);
#pragma unroll
    for (int off = 32; off >= 1; off >>= 1) p += __shfl_xor(p, off, 64);
    float v = p + bf2f(canon[OFF_BFC + cls]);
    res[cls] = (fabsf(v) < 1e30f) ? v : 0.f;
  }
  if (BF) {
    if (lane < 5) {
      u32 pk = (u32)f2bf(res[lane * 2]) | ((u32)f2bf(res[lane * 2 + 1]) << 16);
      ((u32*)out)[(size_t)n * 5 + lane] = pk;
    }
  } else {
    if (lane < 10) ((float*)out)[(size_t)n * 10 + lane] = res[lane];
  }
}

// ---- CSR build ----
__global__ void k_zero(int* __restrict__ p, int cnt) {
  int i = blockIdx.x * 256 + threadIdx.x;
  if (i < cnt) p[i] = 0;
}

__global__ void k_hist(const int* __restrict__ ei, int* __restrict__ deg) {
  int i = blockIdx.x * 256 + threadIdx.x;
  if (i < ETOT) {
    int d = (i < EDG) ? ei[EDG + i] : (i - EDG);
    d = clampi(d, 0, NSEQ - 1);
    atomicAdd(&deg[d], 1);
  }
}

// single-block exclusive scan: 20 elems/thread serial + wave shuffle scan +
// 16-entry LDS cross-wave combine
__global__ __launch_bounds__(1024) void k_scan(const int* __restrict__ deg,
                                               int* __restrict__ offs, int* __restrict__ cur) {
  __shared__ int wsum[16];
  const int tid = threadIdx.x;
  const int lane = tid & 63, wv = tid >> 6;
  const int CHUNK = 20;
  int base = tid * CHUNK;
  int loc[20];
  int s = 0;
#pragma unroll
  for (int i = 0; i < CHUNK; ++i) {
    int idx = base + i;
    int v = (idx < NSEQ) ? deg[idx] : 0;
    loc[i] = s;
    s += v;
  }
  int inc = s;
#pragma unroll
  for (int off = 1; off < 64; off <<= 1) {
    int t2 = __shfl_up(inc, off, 64);
    if (lane >= off) inc += t2;
  }
  if (lane == 63) wsum[wv] = inc;
  __syncthreads();
  int wbase = 0;
  for (int i = 0; i < wv; ++i) wbase += wsum[i];
  int tbase = wbase + inc - s;
#pragma unroll
  for (int i = 0; i < CHUNK; ++i) {
    int idx = base + i;
    if (idx < NSEQ) {
      int st = tbase + loc[i];
      offs[idx] = st;
      cur[idx] = st;
    }
  }
  if (tid == 0) offs[NSEQ] = ETOT;
}

__global__ void k_scatter(const int* __restrict__ ei, int* __restrict__ cur,
                          int* __restrict__ csr) {
  int i = blockIdx.x * 256 + threadIdx.x;
  if (i < ETOT) {
    int s, d;
    if (i < EDG) { s = ei[i]; d = ei[EDG + i]; }
    else { s = i - EDG; d = s; }
    d = clampi(d, 0, NSEQ - 1);
    int pos = atomicAdd(&cur[d], 1);
    pos = clampi(pos, 0, ETOT - 1);
    csr[pos] = s;
  }
}

extern "C" void kernel_launch(void* const* d_in, const int* in_sizes, int n_in,
                              void* d_out, int out_size, void* d_ws, size_t ws_size,
                              hipStream_t stream) {
  (void)in_sizes; (void)n_in;
  const void* x     = d_in[0];
  const int* lengths= (const int*)d_in[1];
  const int* ei     = (const int*)d_in[2];

  const size_t NEED = 45769344u;
  if (ws_size < NEED) {
    k_fill0<<<(out_size + 255) / 256, 256, 0, stream>>>((u16*)d_out, out_size);
    return;
  }

  char* w = (char*)d_ws;
  size_t o = 0;
  auto alloc = [&](size_t b) { char* p = w + o; o += (b + 255) & ~(size_t)255; return p; };
  int*  flag = (int*)  alloc(256);
  u16*  canon= (u16*)  alloc(1048576);
  int*  deg  = (int*)  alloc((size_t)NSEQ * 4);
  int*  offs = (int*)  alloc((size_t)(NSEQ + 1) * 4);
  int*  cur  = (int*)  alloc((size_t)NSEQ * 4);
  int*  csr  = (int*)  alloc((size_t)ETOT * 4);
  float* als1= (float*)alloc((size_t)NSEQ * 4 * 4);
  float* ald1= (float*)alloc((size_t)NSEQ * 4 * 4);
  char* regB = alloc((size_t)NSEQ * 512 * 2);            // xh1 / later xh2,h2,als2,ald2
  u16*  xh1  = (u16*)regB;
  u16*  xh2  = (u16*)regB;
  float* h2  = (float*)(regB + (size_t)NSEQ * 128 * 2);
  float* als2= (float*)(regB + (size_t)NSEQ * 128 * 2 + (size_t)NSEQ * 128 * 4);
  float* ald2= als2 + NSEQ;
  char* regA = alloc((size_t)NSEQ * 256 * 2);            // hcat / later h1 (w/ ext)
  u16*  hcat = (u16*)regA;
  u16*  h1   = (u16*)regA;
  alloc((size_t)NSEQ * 256 * 2);                         // h1 extension

  // length-sort scratch lives in regB (dead until k_gemm #1)
  int* lperm = (int*)regB;                       // 80000 B
  int* lcnt  = (int*)(regB + 80128);             // 32 ints
  int* lcur  = (int*)(regB + 80256);             // 32 ints

  k_detect<<<1, 64, 0, stream>>>((const u32*)x, flag);
  CvtArgs ca;
  const int srcIdx[16] = {3, 4, 5, 6, 7, 8, 9, 13, 10, 11, 12, 14, 15, 16, 17, 18};
  const int offv[16]   = {OFF_WIHF, OFF_WHHF, OFF_BF, OFF_WIHB, OFF_WHHB, OFF_BB,
                          OFF_W1, OFF_W2, OFF_A1S, OFF_A1D, OFF_B1,
                          OFF_A2S, OFF_A2D, OFF_B2, OFF_WFC, OFF_BFC};
  const int cntv[16]   = {65536, 65536, 512, 65536, 65536, 512,
                          131072, 65536, 512, 512, 512, 128, 128, 128, 1280, 10};
  for (int i = 0; i < 16; ++i) { ca.src[i] = d_in[srcIdx[i]]; ca.off[i] = offv[i]; ca.cnt[i] = cntv[i]; }
  k_cvt<1><<<256, 256, 0, stream>>>(ca, canon, flag);
  k_cvt<0><<<256, 256, 0, stream>>>(ca, canon, flag);

  // length counting-sort -> lperm
  k_zero<<<1, 256, 0, stream>>>(lcnt, 64);
  k_lhist<<<(NSEQ + 255) / 256, 256, 0, stream>>>(lengths, lcnt);
  k_lscan<<<1, 64, 0, stream>>>(lcnt, lcur);
  k_lscatter<<<(NSEQ + 255) / 256, 256, 0, stream>>>(lengths, lcur, lperm);

  // CSR build
  k_zero<<<(NSEQ + 255) / 256, 256, 0, stream>>>(deg, NSEQ);
  k_hist<<<(ETOT + 255) / 256, 256, 0, stream>>>(ei, deg);
  k_scan<<<1, 1024, 0, stream>>>(deg, offs, cur);
  k_scatter<<<(ETOT + 255) / 256, 256, 0, stream>>>(ei, cur, csr);

  k_lstm<1><<<dim3(313, 2), 512, 0, stream>>>(x, lengths, lperm, canon, hcat, flag);
  k_lstm<0><<<dim3(313, 2), 512, 0, stream>>>(x, lengths, lperm, canon, hcat, flag);

  k_gemm<<<dim3(157, 4), 256, 0, stream>>>(hcat, canon + OFF_W1, xh1, NSEQ, 512, 256);
  k_al1<<<5000, 256, 0, stream>>>(xh1, canon, als1, ald1);
  k_agg1<<<NSEQ, 256, 0, stream>>>(xh1, als1, ald1, offs, csr, canon, h1);

  k_gemm<<<dim3(157, 1), 256, 0, stream>>>(h1, canon + OFF_W2, xh2, NSEQ, 128, 512);
  k_al2<<<5000, 256, 0, stream>>>(xh2, canon, als2, ald2);
  k_agg2<<<5000, 256, 0, stream>>>(xh2, als2, ald2, offs, csr, canon, h2);

  k_fc<1><<<5000, 256, 0, stream>>>(h2, canon, d_out, flag);
  k_fc<0><<<5000, 256, 0, stream>>>(h2, canon, d_out, flag);
}